// Round 6
// baseline (460.965 us; speedup 1.0000x reference)
//
#include <hip/hip_runtime.h>
#include <hip/hip_bf16.h>
#include <stdint.h>

typedef __bf16 bf16x8 __attribute__((ext_vector_type(8)));
typedef float  f32x4  __attribute__((ext_vector_type(4)));

constexpr int BB   = 2;
constexpr int QL   = 1024;
constexpr int ML   = 1024;
constexpr int KL   = 2048;
constexpr int ED   = 1024;
constexpr int HH   = 16;
constexpr int FF   = 4096;
constexpr size_t MN = 2048u * 1024u;   // rows x cols of the [B*QL, E] activations

__device__ __forceinline__ bf16x8 ld8(const __hip_bfloat16* p) {
    return *reinterpret_cast<const bf16x8*>(p);
}
__device__ __forceinline__ void st8(__hip_bfloat16* p, bf16x8 v) {
    *reinterpret_cast<bf16x8*>(p) = v;
}
__device__ __forceinline__ f32x4 mfma16(bf16x8 a, bf16x8 b, f32x4 c) {
    return __builtin_amdgcn_mfma_f32_16x16x32_bf16(a, b, c, 0, 0, 0);
}
__device__ __forceinline__ void async16(void* lds, const void* g) {
    __builtin_amdgcn_global_load_lds((__attribute__((address_space(1))) void*)g,
                                     (__attribute__((address_space(3))) void*)lds,
                                     16, 0, 0);
}

// ---------------------------------------------------------------- elementwise
// blocks [0,2048): cat = bf16(concat(member, w));  [2048,3072): rbf = bf16(r)
__global__ __launch_bounds__(256) void build_cat_r(const float* __restrict__ w,
                                                   const float* __restrict__ mem,
                                                   const float* __restrict__ r,
                                                   __hip_bfloat16* __restrict__ cat,
                                                   __hip_bfloat16* __restrict__ rbf) {
    const int bx = blockIdx.x;
    const float* src;
    __hip_bfloat16* dst;
    size_t g;
    if (bx < 2048) {
        size_t t = (size_t)bx * 256 + threadIdx.x;
        g = t * 8;
        int b   = (int)(g >> 21);               // KL*E = 2^21
        int rem = (int)(g & ((1u << 21) - 1));
        int j = rem >> 10, e = rem & 1023;
        src = (j < ML) ? &mem[((size_t)b * ML + j) * ED + e]
                       : &w[((size_t)b * QL + (j - ML)) * ED + e];
        dst = &cat[g];
    } else {
        g = ((size_t)(bx - 2048) * 256 + threadIdx.x) * 8;
        src = &r[g];
        dst = &rbf[g];
    }
    float4 f0 = *(const float4*)src;
    float4 f1 = *(const float4*)(src + 4);
    union { bf16x8 v; __hip_bfloat16 h[8]; } u;
    u.h[0] = __float2bfloat16(f0.x); u.h[1] = __float2bfloat16(f0.y);
    u.h[2] = __float2bfloat16(f0.z); u.h[3] = __float2bfloat16(f0.w);
    u.h[4] = __float2bfloat16(f1.x); u.h[5] = __float2bfloat16(f1.y);
    u.h[6] = __float2bfloat16(f1.z); u.h[7] = __float2bfloat16(f1.w);
    st8(dst, u.v);
}

// ---------------------------------------------------------------- transposes
// in [K][N] f32 -> out [N][K] bf16 (generic, for W1/W2)
__global__ __launch_bounds__(256) void transpose_cast(const float* __restrict__ in,
                                                      __hip_bfloat16* __restrict__ out,
                                                      int K, int N) {
    __shared__ float tile[32][33];
    const int tx = threadIdx.x & 31, ty = threadIdx.x >> 5;
    const int n0 = blockIdx.x * 32, k0 = blockIdx.y * 32;
#pragma unroll
    for (int i = 0; i < 4; ++i)
        tile[ty + i * 8][tx] = in[(size_t)(k0 + ty + i * 8) * N + n0 + tx];
    __syncthreads();
#pragma unroll
    for (int i = 0; i < 4; ++i)
        out[(size_t)(n0 + ty + i * 8) * K + k0 + tx] = __float2bfloat16(tile[tx][ty + i * 8]);
}

// five 1024x1024 weight transposes in one launch: z=0..3 -> wqkvT slots (Wq,Wk,Wv,Wr), z=4 -> wot
__global__ __launch_bounds__(256) void tc5(const float* __restrict__ s0, const float* __restrict__ s1,
                                           const float* __restrict__ s2, const float* __restrict__ s3,
                                           const float* __restrict__ s4,
                                           __hip_bfloat16* __restrict__ wqkvT,
                                           __hip_bfloat16* __restrict__ wot) {
    __shared__ float tile[32][33];
    const int z = blockIdx.z;
    const float* in = (z == 0) ? s0 : (z == 1) ? s1 : (z == 2) ? s2 : (z == 3) ? s3 : s4;
    __hip_bfloat16* out = (z == 4) ? wot : wqkvT + (size_t)z * 1024 * 1024;
    const int tx = threadIdx.x & 31, ty = threadIdx.x >> 5;
    const int n0 = blockIdx.x * 32, k0 = blockIdx.y * 32;
#pragma unroll
    for (int i = 0; i < 4; ++i)
        tile[ty + i * 8][tx] = in[(size_t)(k0 + ty + i * 8) * 1024 + n0 + tx];
    __syncthreads();
#pragma unroll
    for (int i = 0; i < 4; ++i)
        out[(size_t)(n0 + ty + i * 8) * 1024 + k0 + tx] = __float2bfloat16(tile[tx][ty + i * 8]);
}

// v [B, KL, H*DH] bf16 -> vt [B*H, DH, KL] bf16
__global__ __launch_bounds__(256) void transpose_v(const __hip_bfloat16* __restrict__ v,
                                                   __hip_bfloat16* __restrict__ vt) {
    __shared__ __hip_bfloat16 tile[32][33];
    const int tx = threadIdx.x & 31, ty = threadIdx.x >> 5;
    const int s = blockIdx.z, b = s >> 4, h = s & 15;
    const int j0 = blockIdx.x * 32, d0 = blockIdx.y * 32;
#pragma unroll
    for (int i = 0; i < 4; ++i)
        tile[ty + i * 8][tx] =
            v[((size_t)b * KL + j0 + ty + i * 8) * 1024 + h * 64 + d0 + tx];
    __syncthreads();
#pragma unroll
    for (int i = 0; i < 4; ++i)
        vt[((size_t)s * 64 + d0 + ty + i * 8) * KL + j0 + tx] = tile[tx][ty + i * 8];
}

// ---------------------------------------------------------------- GEMM core
// C[.,N] = A[.,lda] @ Bt[.,ldb]^T over kLen cols starting at z*kLen (if SK).
// EPI: 0 = f32 out, 2 = bf16 relu out
template <int EPI, bool SK>
__global__ __launch_bounds__(256) void gemm_bt(const __hip_bfloat16* __restrict__ A,
                                               const __hip_bfloat16* __restrict__ Bt,
                                               void* __restrict__ Cv,
                                               int N, int kLen, int lda, int ldb) {
    __shared__ __align__(16) __hip_bfloat16 sA[128 * 32];
    __shared__ __align__(16) __hip_bfloat16 sB[128 * 32];
    const int tid = threadIdx.x;
    const int lane = tid & 63;
    const int l16 = lane & 15, quad = lane >> 4;
    const int wv = tid >> 6;
    const int wm = wv >> 1, wn = wv & 1;
    const int bm = blockIdx.y * 128, bn = blockIdx.x * 128;
    const int kOff = SK ? blockIdx.z * kLen : 0;
    const int c0 = tid, c1 = 256 + tid;
    const int r0 = c0 >> 2, o0 = (c0 & 3) * 8;
    const int r1 = c1 >> 2, o1 = (c1 & 3) * 8;
    f32x4 acc[4][4] = {};
    for (int k0 = 0; k0 < kLen; k0 += 32) {
        async16(&sA[c0 * 8], A + (size_t)(bm + r0) * lda + kOff + k0 + o0);
        async16(&sA[c1 * 8], A + (size_t)(bm + r1) * lda + kOff + k0 + o1);
        async16(&sB[c0 * 8], Bt + (size_t)(bn + r0) * ldb + kOff + k0 + o0);
        async16(&sB[c1 * 8], Bt + (size_t)(bn + r1) * ldb + kOff + k0 + o1);
        __syncthreads();
        bf16x8 af[4], bfr[4];
#pragma unroll
        for (int i = 0; i < 4; ++i)
            af[i] = ld8(&sA[(wm * 64 + i * 16 + l16) * 32 + quad * 8]);
#pragma unroll
        for (int j = 0; j < 4; ++j)
            bfr[j] = ld8(&sB[(wn * 64 + j * 16 + l16) * 32 + quad * 8]);
#pragma unroll
        for (int i = 0; i < 4; ++i)
#pragma unroll
            for (int j = 0; j < 4; ++j)
                acc[i][j] = mfma16(af[i], bfr[j], acc[i][j]);
        __syncthreads();
    }
#pragma unroll
    for (int i = 0; i < 4; ++i)
#pragma unroll
        for (int j = 0; j < 4; ++j)
#pragma unroll
            for (int rg = 0; rg < 4; ++rg) {
                size_t row = bm + wm * 64 + i * 16 + quad * 4 + rg;
                size_t col = bn + wn * 64 + j * 16 + l16;
                float v = acc[i][j][rg];
                if (EPI == 0) {
                    float* C = (float*)Cv + (SK ? (size_t)blockIdx.z * MN : 0);
                    C[row * N + col] = v;
                } else {
                    __hip_bfloat16* C = (__hip_bfloat16*)Cv;
                    C[row * N + col] = __float2bfloat16(fmaxf(v, 0.f));
                }
            }
}

// ---------------------------------------------------------------- fused QKV+R GEMM
// regions by bn: 0=Q (rows: w part only, +biases), 1=K, 2=V, 3=R (A=rbf)
__global__ __launch_bounds__(256) void gemm_qkvr(const __hip_bfloat16* __restrict__ cat,
                                                 const __hip_bfloat16* __restrict__ rbf,
                                                 const __hip_bfloat16* __restrict__ Bt,
                                                 __hip_bfloat16* __restrict__ qwb,
                                                 __hip_bfloat16* __restrict__ qrb,
                                                 __hip_bfloat16* __restrict__ kbuf,
                                                 __hip_bfloat16* __restrict__ vbuf,
                                                 __hip_bfloat16* __restrict__ rpb,
                                                 const float* __restrict__ rwb,
                                                 const float* __restrict__ rrb) {
    const int bm = blockIdx.y * 128, bn = blockIdx.x * 128;
    const int region = blockIdx.x >> 3;
    if (region == 0 && (bm & 2047) < 1024) return;   // Q only for the w rows
    if (region == 3 && bm >= 2048) return;           // R has 2048 rows
    const __hip_bfloat16* A = (region == 3) ? rbf : cat;
    __shared__ __align__(16) __hip_bfloat16 sA[128 * 32];
    __shared__ __align__(16) __hip_bfloat16 sB[128 * 32];
    const int tid = threadIdx.x;
    const int lane = tid & 63;
    const int l16 = lane & 15, quad = lane >> 4;
    const int wv = tid >> 6;
    const int wm = wv >> 1, wn = wv & 1;
    const int c0 = tid, c1 = 256 + tid;
    const int r0 = c0 >> 2, o0 = (c0 & 3) * 8;
    const int r1 = c1 >> 2, o1 = (c1 & 3) * 8;
    f32x4 acc[4][4] = {};
    for (int k0 = 0; k0 < 1024; k0 += 32) {
        async16(&sA[c0 * 8], A + (size_t)(bm + r0) * 1024 + k0 + o0);
        async16(&sA[c1 * 8], A + (size_t)(bm + r1) * 1024 + k0 + o1);
        async16(&sB[c0 * 8], Bt + (size_t)(bn + r0) * 1024 + k0 + o0);
        async16(&sB[c1 * 8], Bt + (size_t)(bn + r1) * 1024 + k0 + o1);
        __syncthreads();
        bf16x8 af[4], bfr[4];
#pragma unroll
        for (int i = 0; i < 4; ++i)
            af[i] = ld8(&sA[(wm * 64 + i * 16 + l16) * 32 + quad * 8]);
#pragma unroll
        for (int j = 0; j < 4; ++j)
            bfr[j] = ld8(&sB[(wn * 64 + j * 16 + l16) * 32 + quad * 8]);
#pragma unroll
        for (int i = 0; i < 4; ++i)
#pragma unroll
            for (int j = 0; j < 4; ++j)
                acc[i][j] = mfma16(af[i], bfr[j], acc[i][j]);
        __syncthreads();
    }
#pragma unroll
    for (int j = 0; j < 4; ++j) {
        const int col = bn + wn * 64 + j * 16 + l16;
        float bw = 0.f, br = 0.f;
        if (region == 0) { bw = rwb[col]; br = rrb[col]; }
#pragma unroll
        for (int i = 0; i < 4; ++i)
#pragma unroll
            for (int rg = 0; rg < 4; ++rg) {
                const int row = bm + wm * 64 + i * 16 + quad * 4 + rg;
                const int bb = row >> 11, jr = row & 2047;
                float v = acc[i][j][rg];
                if (region == 0) {
                    size_t o = ((size_t)(bb * 1024 + (jr - 1024))) * 1024 + col;
                    qwb[o] = __float2bfloat16(v + bw);
                    qrb[o] = __float2bfloat16(v + br);
                } else if (region == 1) {
                    kbuf[((size_t)(bb * 2048 + jr)) * 1024 + (col - 1024)] = __float2bfloat16(v);
                } else if (region == 2) {
                    vbuf[((size_t)(bb * 2048 + jr)) * 1024 + (col - 2048)] = __float2bfloat16(v);
                } else {
                    rpb[(size_t)row * 1024 + (col - 3072)] = __float2bfloat16(v);
                }
            }
    }
}

// ---------------------------------------------------------------- flash attention v6
// = round-2's flash_attn2 (best measured: 120.7 us) + XCD-aware flat-grid swizzle.
// Block: 128 threads = 2 waves, 64 q-rows (32/wave). LDS-staged K + rp band,
// V frags from global (L2-resident under the swizzle). j-split x2, m=0 softmax.
__global__ __launch_bounds__(128, 2) void flash_attn6(
        const __hip_bfloat16* __restrict__ qw, const __hip_bfloat16* __restrict__ qr,
        const __hip_bfloat16* __restrict__ kbuf, const __hip_bfloat16* __restrict__ vtb,
        const __hip_bfloat16* __restrict__ rpb,
        float* __restrict__ Opart, float* __restrict__ lpart) {
    __shared__ __align__(16) __hip_bfloat16 sk[64][72];
    __shared__ __align__(16) __hip_bfloat16 srp[128][72];
    __shared__ __align__(16) __hip_bfloat16 spb[2][32][72];
    const int tid = threadIdx.x, wv = tid >> 6, lane = tid & 63;
    const int l16 = lane & 15, quad = lane >> 4;
    // ---- XCD swizzle: id&7 -> XCD (round-robin dispatch); 4 (b,h) pairs per XCD.
    const int id    = blockIdx.x;          // 0..1023
    const int xcd   = id & 7;
    const int rest  = id >> 3;             // 0..127
    const int grp   = rest >> 5;           // 0..3
    const int local = rest & 31;           // 0..31
    const int p     = grp * 8 + xcd;       // (b*HH+h) 0..31
    const int b = p >> 4, h = p & 15;
    const int qb = local >> 1, chunk = local & 1;
    const int i0b = qb * 64, i0w = i0b + wv * 32;

    bf16x8 qaw[2][2], qar[2][2];
#pragma unroll
    for (int g = 0; g < 2; ++g)
#pragma unroll
        for (int kf = 0; kf < 2; ++kf) {
            size_t qi = ((size_t)(b * QL + i0w + g * 16 + l16)) * 1024 + h * 64 + kf * 32 + quad * 8;
            qaw[g][kf] = ld8(&qw[qi]);
            qar[g][kf] = ld8(&qr[qi]);
        }
    f32x4 oacc[2][4] = {};
    f32x4 lacc[2] = {};
    union { bf16x8 v; __hip_bfloat16 h8[8]; } ou;
#pragma unroll
    for (int j = 0; j < 8; ++j) ou.h8[j] = __float2bfloat16(l16 == 0 ? 1.f : 0.f);
    const bf16x8 onesf = ou.v;

    int srcIdx[4], selr[4];
#pragma unroll
    for (int r = 0; r < 4; ++r) {
        int s = l16 + 15 - (quad * 4 + r);
        selr[r] = s >> 4;
        srcIdx[r] = (lane & 48) | (s & 15);
    }
    const int T = qb + 17, Ta = T >> 1;
    const int t0 = chunk ? Ta : 0, t1 = chunk ? T : Ta;
    const int rbase = 32 - wv * 32;

    for (int jt = t0; jt < t1; ++jt) {
        const int j0 = jt * 64;
        const int ub = j0 - i0b + 960;
        // ---- stage K tile and RP band
#pragma unroll
        for (int pp = 0; pp < 4; ++pp) {
            int cc = pp * 128 + tid, row = cc >> 3, off = (cc & 7) * 8;
            st8(&sk[row][off], ld8(&kbuf[((size_t)(b * KL + j0 + row)) * 1024 + h * 64 + off]));
        }
#pragma unroll
        for (int pp = 0; pp < 8; ++pp) {
            int cc = pp * 128 + tid, row = cc >> 3, off = (cc & 7) * 8;
            int u = ub + row;
            if (u < KL) {
                st8(&srp[row][off], ld8(&rpb[(size_t)u * 1024 + h * 64 + off]));
            } else {
                union { bf16x8 v; uint32_t w[4]; } z;
                z.w[0] = z.w[1] = z.w[2] = z.w[3] = 0u;
                st8(&srp[row][off], z.v);
            }
        }
        // ---- V fragments straight from global (L2-resident), overlap with barrier
        bf16x8 vvf[4][2];
#pragma unroll
        for (int dt = 0; dt < 4; ++dt) {
            size_t vr = ((size_t)((b * HH + h) * 64 + dt * 16 + l16)) * 2048 + j0 + quad * 8;
            vvf[dt][0] = ld8(&vtb[vr]);
            vvf[dt][1] = ld8(&vtb[vr + 32]);
        }
        __syncthreads();
        // ---- AC = (q + r_w_bias) . k
        f32x4 sfr[2][4];
#pragma unroll
        for (int nt = 0; nt < 4; ++nt) {
            bf16x8 b0 = ld8(&sk[nt * 16 + l16][quad * 8]);
            bf16x8 b1 = ld8(&sk[nt * 16 + l16][32 + quad * 8]);
#pragma unroll
            for (int g = 0; g < 2; ++g) {
                f32x4 z = {};
                z = mfma16(qaw[g][0], b0, z);
                z = mfma16(qaw[g][1], b1, z);
                sfr[g][nt] = z;
            }
        }
        // ---- BD band fragments (shared across groups)
        bf16x8 bF0[6], bF1[6];
#pragma unroll
        for (int t = 0; t < 6; ++t) {
            int rr = rbase + t * 16 + l16;
            bF0[t] = ld8(&srp[rr][quad * 8]);
            bF1[t] = ld8(&srp[rr][32 + quad * 8]);
        }
#pragma unroll
        for (int g = 0; g < 2; ++g) {
            f32x4 bd[5];
#pragma unroll
            for (int t = 0; t < 5; ++t) {
                int ts = t + 1 - g;
                f32x4 z = {};
                z = mfma16(qar[g][0], bF0[ts], z);
                z = mfma16(qar[g][1], bF1[ts], z);
                bd[t] = z;
            }
            float pre[5][4];
#pragma unroll
            for (int t = 0; t < 5; ++t)
#pragma unroll
                for (int r = 0; r < 4; ++r)
                    pre[t][r] = __shfl(bd[t][r], srcIdx[r], 64);
#pragma unroll
            for (int nt = 0; nt < 4; ++nt)
#pragma unroll
                for (int r = 0; r < 4; ++r) {
                    float bdv = selr[r] ? pre[nt + 1][r] : pre[nt][r];
                    float sv = (sfr[g][nt][r] + bdv) * 0.03125f;
                    int ii = i0w + g * 16 + quad * 4 + r;
                    int jj = j0 + nt * 16 + l16;
                    float p_ = (jj <= ii + ML) ? __expf(sv) : 0.f;
                    spb[wv][g * 16 + quad * 4 + r][nt * 16 + l16] = __float2bfloat16(p_);
                }
        }
        // ---- P @ [V | 1]
#pragma unroll
        for (int g = 0; g < 2; ++g) {
            bf16x8 pa0 = ld8(&spb[wv][g * 16 + l16][quad * 8]);
            bf16x8 pa1 = ld8(&spb[wv][g * 16 + l16][32 + quad * 8]);
            lacc[g] = mfma16(pa0, onesf, lacc[g]);
            lacc[g] = mfma16(pa1, onesf, lacc[g]);
#pragma unroll
            for (int dt = 0; dt < 4; ++dt) {
                oacc[g][dt] = mfma16(pa0, vvf[dt][0], oacc[g][dt]);
                oacc[g][dt] = mfma16(pa1, vvf[dt][1], oacc[g][dt]);
            }
        }
        __syncthreads();
    }
    // ---- unnormalized partial out + l  (group index: chunk*2 + b, 4 groups)
    const size_t obase = ((size_t)((chunk * 2 + b) * HH + h)) * (1024 * 64);
#pragma unroll
    for (int g = 0; g < 2; ++g)
#pragma unroll
        for (int dt = 0; dt < 4; ++dt)
#pragma unroll
            for (int r = 0; r < 4; ++r) {
                int q = i0w + g * 16 + quad * 4 + r;
                Opart[obase + (size_t)q * 64 + dt * 16 + l16] = oacc[g][dt][r];
            }
    if (l16 == 0) {
        const size_t lbase = ((size_t)((chunk * 2 + b) * HH + h)) * 1024;
#pragma unroll
        for (int g = 0; g < 2; ++g)
#pragma unroll
            for (int r = 0; r < 4; ++r) {
                int q = i0w + g * 16 + quad * 4 + r;
                lpart[lbase + q] = lacc[g][r];
            }
    }
}

// combine 2 j-chunks: og = (O0+O1)/(l0+l1), layout [b][q][h*64+d] bf16
__global__ __launch_bounds__(256) void combine_attn(const float* __restrict__ Opart,
                                                    const float* __restrict__ lpart,
                                                    __hip_bfloat16* __restrict__ og) {
    size_t t = (size_t)blockIdx.x * 256 + threadIdx.x;
    size_t e4 = t * 4;
    int d  = (int)(e4 & 63);
    int q  = (int)((e4 >> 6) & 1023);
    int hh = (int)((e4 >> 16) & 15);
    int bb = (int)(e4 >> 20);
    float ox = 0.f, oy = 0.f, oz = 0.f, ow = 0.f, l = 0.f;
#pragma unroll
    for (int c = 0; c < 2; ++c) {
        size_t gsel = (size_t)((c * 2 + bb) * HH + hh);
        float4 o = *(const float4*)&Opart[gsel * (1024 * 64) + (size_t)q * 64 + d];
        ox += o.x; oy += o.y; oz += o.z; ow += o.w;
        l += lpart[gsel * 1024 + q];
    }
    float inv = 1.f / l;
    union { __hip_bfloat16 h[4]; uint2 u; } o;
    o.h[0] = __float2bfloat16(ox * inv);
    o.h[1] = __float2bfloat16(oy * inv);
    o.h[2] = __float2bfloat16(oz * inv);
    o.h[3] = __float2bfloat16(ow * inv);
    *(uint2*)&og[((size_t)bb * 1024 + q) * 1024 + hh * 64 + d] = o.u;
}

// ---------------------------------------------------------------- layernorm
// x = res + sum_{z<NP} parts[z*MN + .] ; out = LN(x); writes f32 + optional bf16
template <int NP, bool WB>
__global__ __launch_bounds__(256) void add_ln_k(const float* __restrict__ res,
                                                const float* __restrict__ parts,
                                                const float* __restrict__ gam,
                                                const float* __restrict__ bet,
                                                float* __restrict__ of,
                                                __hip_bfloat16* __restrict__ ob) {
    const int tid = threadIdx.x;
    const size_t base = (size_t)blockIdx.x * ED;
    const int col = tid * 4;
    float4 va = *(const float4*)&res[base + col];
    float x0 = va.x, x1 = va.y, x2 = va.z, x3 = va.w;
#pragma unroll
    for (int z = 0; z < NP; ++z) {
        float4 p = *(const float4*)&parts[(size_t)z * MN + base + col];
        x0 += p.x; x1 += p.y; x2 += p.z; x3 += p.w;
    }
    float s1 = x0 + x1 + x2 + x3;
    float s2 = x0 * x0 + x1 * x1 + x2 * x2 + x3 * x3;
    for (int o = 32; o > 0; o >>= 1) {
        s1 += __shfl_down(s1, o, 64);
        s2 += __shfl_down(s2, o, 64);
    }
    __shared__ float p1[4], p2[4];
    if ((tid & 63) == 0) { p1[tid >> 6] = s1; p2[tid >> 6] = s2; }
    __syncthreads();
    float S1 = p1[0] + p1[1] + p1[2] + p1[3];
    float S2 = p2[0] + p2[1] + p2[2] + p2[3];
    float mu = S1 * (1.0f / ED);
    float var = S2 * (1.0f / ED) - mu * mu;
    float rs = rsqrtf(var + 1e-3f);
    float4 g4 = *(const float4*)&gam[col];
    float4 b4 = *(const float4*)&bet[col];
    float y0 = (x0 - mu) * rs * g4.x + b4.x;
    float y1 = (x1 - mu) * rs * g4.y + b4.y;
    float y2 = (x2 - mu) * rs * g4.z + b4.z;
    float y3 = (x3 - mu) * rs * g4.w + b4.w;
    *(float4*)&of[base + col] = make_float4(y0, y1, y2, y3);
    if (WB) {
        ob[base + col + 0] = __float2bfloat16(y0);
        ob[base + col + 1] = __float2bfloat16(y1);
        ob[base + col + 2] = __float2bfloat16(y2);
        ob[base + col + 3] = __float2bfloat16(y3);
    }
}

// ---------------------------------------------------------------- launch
extern "C" void kernel_launch(void* const* d_in, const int* in_sizes, int n_in,
                              void* d_out, int out_size, void* d_ws, size_t ws_size,
                              hipStream_t stream) {
    const float* w   = (const float*)d_in[0];
    const float* r   = (const float*)d_in[1];
    const float* mem = (const float*)d_in[2];
    const float* Wq  = (const float*)d_in[4];
    const float* Wk  = (const float*)d_in[5];
    const float* Wv  = (const float*)d_in[6];
    const float* Wr  = (const float*)d_in[7];
    const float* Wo  = (const float*)d_in[8];
    const float* rwb = (const float*)d_in[9];
    const float* rrb = (const float*)d_in[10];
    const float* g1  = (const float*)d_in[11];
    const float* b1  = (const float*)d_in[12];
    const float* W1  = (const float*)d_in[13];
    const float* W2  = (const float*)d_in[14];
    const float* g2  = (const float*)d_in[15];
    const float* b2  = (const float*)d_in[16];

    char* ws = (char*)d_ws;
    size_t off = 0;
    auto alloc = [&](size_t bytes) -> void* {
        void* p = ws + off;
        off += (bytes + 255) & ~(size_t)255;
        return p;
    };
    // persistent
    __hip_bfloat16* wqkvT = (__hip_bfloat16*)alloc((size_t)4096 * 1024 * 2); // Wq|Wk|Wv|Wr ^T
    __hip_bfloat16* wot   = (__hip_bfloat16*)alloc((size_t)ED * ED * 2);
    __hip_bfloat16* w1t   = (__hip_bfloat16*)alloc((size_t)FF * ED * 2);
    __hip_bfloat16* w2t   = (__hip_bfloat16*)alloc((size_t)ED * FF * 2);
    __hip_bfloat16* qwb   = (__hip_bfloat16*)alloc((size_t)BB * QL * ED * 2);
    __hip_bfloat16* qrb   = (__hip_bfloat16*)alloc((size_t)BB * QL * ED * 2);
    __hip_bfloat16* vtb   = (__hip_bfloat16*)alloc((size_t)BB * KL * ED * 2);
    __hip_bfloat16* rpb   = (__hip_bfloat16*)alloc((size_t)KL * ED * 2);
    __hip_bfloat16* og    = (__hip_bfloat16*)alloc((size_t)BB * QL * ED * 2);
    // regionA: cat | xf
    char* regA = (char*)alloc((size_t)BB * KL * ED * 2);
    __hip_bfloat16* cat = (__hip_bfloat16*)regA;
    float*          xf  = (float*)regA;
    // regionB: rbf | xb
    char* regB = (char*)alloc((size_t)KL * ED * 2);
    __hip_bfloat16* rbf = (__hip_bfloat16*)regB;
    __hip_bfloat16* xb  = (__hip_bfloat16*)regB;
    // regionC: kbuf+vbuf | y1
    char* regC = (char*)alloc((size_t)BB * QL * FF * 2);
    __hip_bfloat16* kbuf = (__hip_bfloat16*)regC;
    __hip_bfloat16* vbuf = (__hip_bfloat16*)(regC + (size_t)BB * KL * ED * 2);
    __hip_bfloat16* y1   = (__hip_bfloat16*)regC;
    // regionE: (Opart[4 groups]+lpart) | o_part(4xMN f32) | f_part(4xMN f32)
    const size_t opartBytes = (size_t)4 * HH * QL * 64 * 4;   // 16.8 MB (4 groups)
    const size_t lpartBytes = (size_t)4 * HH * QL * 4;        // 0.25 MB
    size_t regEsz = opartBytes + lpartBytes;
    if (regEsz < (size_t)4 * MN * 4) regEsz = (size_t)4 * MN * 4;
    char* regE = (char*)alloc(regEsz);
    float* Opart  = (float*)regE;
    float* lpart  = (float*)(regE + opartBytes);
    float* o_part = (float*)regE;
    float* f_part = (float*)regE;
    if (off > ws_size) return;  // diagnostic: ws too small -> zeros -> fail loud

    // prep: casts + weight transposes (4 launches)
    build_cat_r<<<3072, 256, 0, stream>>>(w, mem, r, cat, rbf);
    tc5<<<dim3(32, 32, 5), 256, 0, stream>>>(Wq, Wk, Wv, Wr, Wo, wqkvT, wot);
    transpose_cast<<<dim3(128, 32), 256, 0, stream>>>(W1, w1t, 1024, 4096);
    transpose_cast<<<dim3(32, 128), 256, 0, stream>>>(W2, w2t, 4096, 1024);

    // fused Q/K/V/R projection (+Q bias epilogue)
    gemm_qkvr<<<dim3(32, 32), 256, 0, stream>>>(cat, rbf, wqkvT, qwb, qrb, kbuf, vbuf, rpb,
                                                rwb, rrb);
    transpose_v<<<dim3(64, 2, 32), 256, 0, stream>>>(vbuf, vtb);

    // attention (r2 structure + XCD swizzle, j-split x2) + combine
    flash_attn6<<<dim3(1024), 128, 0, stream>>>(qwb, qrb, kbuf, vtb, rpb, Opart, lpart);
    combine_attn<<<2048, 256, 0, stream>>>(Opart, lpart, og);

    // output projection (split-K 4) + LN1
    gemm_bt<0, true><<<dim3(8, 16, 4), 256, 0, stream>>>(og, wot, o_part, 1024, 256, 1024, 1024);
    add_ln_k<4, true><<<2048, 256, 0, stream>>>(w, o_part, g1, b1, xf, xb);

    // FFN + LN2
    gemm_bt<2, false><<<dim3(32, 16, 1), 256, 0, stream>>>(xb, w1t, y1, 4096, 1024, 1024, 1024);
    gemm_bt<0, true><<<dim3(8, 16, 4), 256, 0, stream>>>(y1, w2t, f_part, 1024, 1024, 4096, 4096);
    add_ln_k<4, false><<<2048, 256, 0, stream>>>(xf, f_part, g2, b2, (float*)d_out, nullptr);
}

// Round 7
// 393.990 us; speedup vs baseline: 1.1700x; 1.1700x over previous
//
#include <hip/hip_runtime.h>
#include <hip/hip_bf16.h>
#include <stdint.h>

typedef __bf16 bf16x8 __attribute__((ext_vector_type(8)));
typedef float  f32x4  __attribute__((ext_vector_type(4)));

constexpr int BB   = 2;
constexpr int QL   = 1024;
constexpr int ML   = 1024;
constexpr int KL   = 2048;
constexpr int ED   = 1024;
constexpr int HH   = 16;
constexpr int FF   = 4096;
constexpr size_t MN = 2048u * 1024u;   // rows x cols of the [B*QL, E] activations

__device__ __forceinline__ bf16x8 ld8(const __hip_bfloat16* p) {
    return *reinterpret_cast<const bf16x8*>(p);
}
__device__ __forceinline__ void st8(__hip_bfloat16* p, bf16x8 v) {
    *reinterpret_cast<bf16x8*>(p) = v;
}
__device__ __forceinline__ f32x4 mfma16(bf16x8 a, bf16x8 b, f32x4 c) {
    return __builtin_amdgcn_mfma_f32_16x16x32_bf16(a, b, c, 0, 0, 0);
}
__device__ __forceinline__ void async16(void* lds, const void* g) {
    __builtin_amdgcn_global_load_lds((__attribute__((address_space(1))) void*)g,
                                     (__attribute__((address_space(3))) void*)lds,
                                     16, 0, 0);
}

// ---------------------------------------------------------------- elementwise
// blocks [0,2048): cat = bf16(concat(member, w));  [2048,3072): rbf = bf16(r)
__global__ __launch_bounds__(256) void build_cat_r(const float* __restrict__ w,
                                                   const float* __restrict__ mem,
                                                   const float* __restrict__ r,
                                                   __hip_bfloat16* __restrict__ cat,
                                                   __hip_bfloat16* __restrict__ rbf) {
    const int bx = blockIdx.x;
    const float* src;
    __hip_bfloat16* dst;
    size_t g;
    if (bx < 2048) {
        size_t t = (size_t)bx * 256 + threadIdx.x;
        g = t * 8;
        int b   = (int)(g >> 21);               // KL*E = 2^21
        int rem = (int)(g & ((1u << 21) - 1));
        int j = rem >> 10, e = rem & 1023;
        src = (j < ML) ? &mem[((size_t)b * ML + j) * ED + e]
                       : &w[((size_t)b * QL + (j - ML)) * ED + e];
        dst = &cat[g];
    } else {
        g = ((size_t)(bx - 2048) * 256 + threadIdx.x) * 8;
        src = &r[g];
        dst = &rbf[g];
    }
    float4 f0 = *(const float4*)src;
    float4 f1 = *(const float4*)(src + 4);
    union { bf16x8 v; __hip_bfloat16 h[8]; } u;
    u.h[0] = __float2bfloat16(f0.x); u.h[1] = __float2bfloat16(f0.y);
    u.h[2] = __float2bfloat16(f0.z); u.h[3] = __float2bfloat16(f0.w);
    u.h[4] = __float2bfloat16(f1.x); u.h[5] = __float2bfloat16(f1.y);
    u.h[6] = __float2bfloat16(f1.z); u.h[7] = __float2bfloat16(f1.w);
    st8(dst, u.v);
}

// ---------------------------------------------------------------- transposes
// in [K][N] f32 -> out [N][K] bf16 (generic, for W1/W2)
__global__ __launch_bounds__(256) void transpose_cast(const float* __restrict__ in,
                                                      __hip_bfloat16* __restrict__ out,
                                                      int K, int N) {
    __shared__ float tile[32][33];
    const int tx = threadIdx.x & 31, ty = threadIdx.x >> 5;
    const int n0 = blockIdx.x * 32, k0 = blockIdx.y * 32;
#pragma unroll
    for (int i = 0; i < 4; ++i)
        tile[ty + i * 8][tx] = in[(size_t)(k0 + ty + i * 8) * N + n0 + tx];
    __syncthreads();
#pragma unroll
    for (int i = 0; i < 4; ++i)
        out[(size_t)(n0 + ty + i * 8) * K + k0 + tx] = __float2bfloat16(tile[tx][ty + i * 8]);
}

// five 1024x1024 weight transposes in one launch: z=0..3 -> wqkvT slots (Wq,Wk,Wv,Wr), z=4 -> wot
__global__ __launch_bounds__(256) void tc5(const float* __restrict__ s0, const float* __restrict__ s1,
                                           const float* __restrict__ s2, const float* __restrict__ s3,
                                           const float* __restrict__ s4,
                                           __hip_bfloat16* __restrict__ wqkvT,
                                           __hip_bfloat16* __restrict__ wot) {
    __shared__ float tile[32][33];
    const int z = blockIdx.z;
    const float* in = (z == 0) ? s0 : (z == 1) ? s1 : (z == 2) ? s2 : (z == 3) ? s3 : s4;
    __hip_bfloat16* out = (z == 4) ? wot : wqkvT + (size_t)z * 1024 * 1024;
    const int tx = threadIdx.x & 31, ty = threadIdx.x >> 5;
    const int n0 = blockIdx.x * 32, k0 = blockIdx.y * 32;
#pragma unroll
    for (int i = 0; i < 4; ++i)
        tile[ty + i * 8][tx] = in[(size_t)(k0 + ty + i * 8) * 1024 + n0 + tx];
    __syncthreads();
#pragma unroll
    for (int i = 0; i < 4; ++i)
        out[(size_t)(n0 + ty + i * 8) * 1024 + k0 + tx] = __float2bfloat16(tile[tx][ty + i * 8]);
}

// v [B, KL, H*DH] bf16 -> vt [B*H, DH, KL] bf16
__global__ __launch_bounds__(256) void transpose_v(const __hip_bfloat16* __restrict__ v,
                                                   __hip_bfloat16* __restrict__ vt) {
    __shared__ __hip_bfloat16 tile[32][33];
    const int tx = threadIdx.x & 31, ty = threadIdx.x >> 5;
    const int s = blockIdx.z, b = s >> 4, h = s & 15;
    const int j0 = blockIdx.x * 32, d0 = blockIdx.y * 32;
#pragma unroll
    for (int i = 0; i < 4; ++i)
        tile[ty + i * 8][tx] =
            v[((size_t)b * KL + j0 + ty + i * 8) * 1024 + h * 64 + d0 + tx];
    __syncthreads();
#pragma unroll
    for (int i = 0; i < 4; ++i)
        vt[((size_t)s * 64 + d0 + ty + i * 8) * KL + j0 + tx] = tile[tx][ty + i * 8];
}

// ---------------------------------------------------------------- GEMM core
// C[.,N] = A[.,lda] @ Bt[.,ldb]^T over kLen cols starting at z*kLen (if SK).
// EPI: 0 = f32 out, 2 = bf16 relu out
template <int EPI, bool SK>
__global__ __launch_bounds__(256) void gemm_bt(const __hip_bfloat16* __restrict__ A,
                                               const __hip_bfloat16* __restrict__ Bt,
                                               void* __restrict__ Cv,
                                               int N, int kLen, int lda, int ldb) {
    __shared__ __align__(16) __hip_bfloat16 sA[128 * 32];
    __shared__ __align__(16) __hip_bfloat16 sB[128 * 32];
    const int tid = threadIdx.x;
    const int lane = tid & 63;
    const int l16 = lane & 15, quad = lane >> 4;
    const int wv = tid >> 6;
    const int wm = wv >> 1, wn = wv & 1;
    const int bm = blockIdx.y * 128, bn = blockIdx.x * 128;
    const int kOff = SK ? blockIdx.z * kLen : 0;
    const int c0 = tid, c1 = 256 + tid;
    const int r0 = c0 >> 2, o0 = (c0 & 3) * 8;
    const int r1 = c1 >> 2, o1 = (c1 & 3) * 8;
    f32x4 acc[4][4] = {};
    for (int k0 = 0; k0 < kLen; k0 += 32) {
        async16(&sA[c0 * 8], A + (size_t)(bm + r0) * lda + kOff + k0 + o0);
        async16(&sA[c1 * 8], A + (size_t)(bm + r1) * lda + kOff + k0 + o1);
        async16(&sB[c0 * 8], Bt + (size_t)(bn + r0) * ldb + kOff + k0 + o0);
        async16(&sB[c1 * 8], Bt + (size_t)(bn + r1) * ldb + kOff + k0 + o1);
        __syncthreads();
        bf16x8 af[4], bfr[4];
#pragma unroll
        for (int i = 0; i < 4; ++i)
            af[i] = ld8(&sA[(wm * 64 + i * 16 + l16) * 32 + quad * 8]);
#pragma unroll
        for (int j = 0; j < 4; ++j)
            bfr[j] = ld8(&sB[(wn * 64 + j * 16 + l16) * 32 + quad * 8]);
#pragma unroll
        for (int i = 0; i < 4; ++i)
#pragma unroll
            for (int j = 0; j < 4; ++j)
                acc[i][j] = mfma16(af[i], bfr[j], acc[i][j]);
        __syncthreads();
    }
#pragma unroll
    for (int i = 0; i < 4; ++i)
#pragma unroll
        for (int j = 0; j < 4; ++j)
#pragma unroll
            for (int rg = 0; rg < 4; ++rg) {
                size_t row = bm + wm * 64 + i * 16 + quad * 4 + rg;
                size_t col = bn + wn * 64 + j * 16 + l16;
                float v = acc[i][j][rg];
                if (EPI == 0) {
                    float* C = (float*)Cv + (SK ? (size_t)blockIdx.z * MN : 0);
                    C[row * N + col] = v;
                } else {
                    __hip_bfloat16* C = (__hip_bfloat16*)Cv;
                    C[row * N + col] = __float2bfloat16(fmaxf(v, 0.f));
                }
            }
}

// ---------------------------------------------------------------- fused QKV+R GEMM
// Flat grid of exactly 768 live blocks (no dead-block early exits):
// [0,128) Q (w rows only, +biases) | [128,384) K | [384,640) V | [640,768) R
__global__ __launch_bounds__(256) void gemm_qkvr(const __hip_bfloat16* __restrict__ cat,
                                                 const __hip_bfloat16* __restrict__ rbf,
                                                 const __hip_bfloat16* __restrict__ Bt,
                                                 __hip_bfloat16* __restrict__ qwb,
                                                 __hip_bfloat16* __restrict__ qrb,
                                                 __hip_bfloat16* __restrict__ kbuf,
                                                 __hip_bfloat16* __restrict__ vbuf,
                                                 __hip_bfloat16* __restrict__ rpb,
                                                 const float* __restrict__ rwb,
                                                 const float* __restrict__ rrb) {
    const int id = blockIdx.x;
    int region, bm, bn;
    if (id < 128) {                      // Q: 16 bm (w rows) x 8 bn
        region = 0;
        int i = id, bmI = i >> 3;
        bm = (bmI >> 3) * 2048 + 1024 + (bmI & 7) * 128;
        bn = (i & 7) * 128;
    } else if (id < 384) {               // K: 32 bm x 8 bn
        region = 1;
        int i = id - 128;
        bm = (i >> 3) * 128;
        bn = (8 + (i & 7)) * 128;
    } else if (id < 640) {               // V: 32 bm x 8 bn
        region = 2;
        int i = id - 384;
        bm = (i >> 3) * 128;
        bn = (16 + (i & 7)) * 128;
    } else {                             // R: 16 bm x 8 bn
        region = 3;
        int i = id - 640;
        bm = (i >> 3) * 128;
        bn = (24 + (i & 7)) * 128;
    }
    const __hip_bfloat16* A = (region == 3) ? rbf : cat;
    __shared__ __align__(16) __hip_bfloat16 sA[128 * 32];
    __shared__ __align__(16) __hip_bfloat16 sB[128 * 32];
    const int tid = threadIdx.x;
    const int lane = tid & 63;
    const int l16 = lane & 15, quad = lane >> 4;
    const int wv = tid >> 6;
    const int wm = wv >> 1, wn = wv & 1;
    const int c0 = tid, c1 = 256 + tid;
    const int r0 = c0 >> 2, o0 = (c0 & 3) * 8;
    const int r1 = c1 >> 2, o1 = (c1 & 3) * 8;
    f32x4 acc[4][4] = {};
    for (int k0 = 0; k0 < 1024; k0 += 32) {
        async16(&sA[c0 * 8], A + (size_t)(bm + r0) * 1024 + k0 + o0);
        async16(&sA[c1 * 8], A + (size_t)(bm + r1) * 1024 + k0 + o1);
        async16(&sB[c0 * 8], Bt + (size_t)(bn + r0) * 1024 + k0 + o0);
        async16(&sB[c1 * 8], Bt + (size_t)(bn + r1) * 1024 + k0 + o1);
        __syncthreads();
        bf16x8 af[4], bfr[4];
#pragma unroll
        for (int i = 0; i < 4; ++i)
            af[i] = ld8(&sA[(wm * 64 + i * 16 + l16) * 32 + quad * 8]);
#pragma unroll
        for (int j = 0; j < 4; ++j)
            bfr[j] = ld8(&sB[(wn * 64 + j * 16 + l16) * 32 + quad * 8]);
#pragma unroll
        for (int i = 0; i < 4; ++i)
#pragma unroll
            for (int j = 0; j < 4; ++j)
                acc[i][j] = mfma16(af[i], bfr[j], acc[i][j]);
        __syncthreads();
    }
#pragma unroll
    for (int j = 0; j < 4; ++j) {
        const int col = bn + wn * 64 + j * 16 + l16;
        float bw = 0.f, br = 0.f;
        if (region == 0) { bw = rwb[col]; br = rrb[col]; }
#pragma unroll
        for (int i = 0; i < 4; ++i)
#pragma unroll
            for (int rg = 0; rg < 4; ++rg) {
                const int row = bm + wm * 64 + i * 16 + quad * 4 + rg;
                const int bb = row >> 11, jr = row & 2047;
                float v = acc[i][j][rg];
                if (region == 0) {
                    size_t o = ((size_t)(bb * 1024 + (jr - 1024))) * 1024 + col;
                    qwb[o] = __float2bfloat16(v + bw);
                    qrb[o] = __float2bfloat16(v + br);
                } else if (region == 1) {
                    kbuf[((size_t)(bb * 2048 + jr)) * 1024 + (col - 1024)] = __float2bfloat16(v);
                } else if (region == 2) {
                    vbuf[((size_t)(bb * 2048 + jr)) * 1024 + (col - 2048)] = __float2bfloat16(v);
                } else {
                    rpb[(size_t)row * 1024 + (col - 3072)] = __float2bfloat16(v);
                }
            }
    }
}

// ---------------------------------------------------------------- flash attention v7
// r2's measured-best structure (grid (32,16,2), 2 waves, LDS-staged K, V from
// global, j-split x2) MINUS the srp LDS stage: rp band fragments load straight
// from global with clamped rows (out-of-range rows only feed causally-masked
// entries: u = j+QL-1-i <= 2047  <=>  j <= i+ML). LDS 36.9 -> 18.4 KB doubles
// residency to 8 blocks/CU (16 waves). No XCD swizzle (measured regression x2).
__global__ __launch_bounds__(128, 2) void flash_attn7(
        const __hip_bfloat16* __restrict__ qw, const __hip_bfloat16* __restrict__ qr,
        const __hip_bfloat16* __restrict__ kbuf, const __hip_bfloat16* __restrict__ vtb,
        const __hip_bfloat16* __restrict__ rpb,
        float* __restrict__ Opart, float* __restrict__ lpart) {
    __shared__ __align__(16) __hip_bfloat16 sk[64][72];
    __shared__ __align__(16) __hip_bfloat16 spb[2][32][72];
    const int tid = threadIdx.x, wv = tid >> 6, lane = tid & 63;
    const int l16 = lane & 15, quad = lane >> 4;
    const int qb = blockIdx.x >> 1, chunk = blockIdx.x & 1;
    const int h = blockIdx.y, b = blockIdx.z;
    const int i0b = qb * 64, i0w = i0b + wv * 32;

    bf16x8 qaw[2][2], qar[2][2];
#pragma unroll
    for (int g = 0; g < 2; ++g)
#pragma unroll
        for (int kf = 0; kf < 2; ++kf) {
            size_t qi = ((size_t)(b * QL + i0w + g * 16 + l16)) * 1024 + h * 64 + kf * 32 + quad * 8;
            qaw[g][kf] = ld8(&qw[qi]);
            qar[g][kf] = ld8(&qr[qi]);
        }
    f32x4 oacc[2][4] = {};
    f32x4 lacc[2] = {};
    union { bf16x8 v; __hip_bfloat16 h8[8]; } ou;
#pragma unroll
    for (int j = 0; j < 8; ++j) ou.h8[j] = __float2bfloat16(l16 == 0 ? 1.f : 0.f);
    const bf16x8 onesf = ou.v;

    int srcIdx[4], selr[4];
#pragma unroll
    for (int r = 0; r < 4; ++r) {
        int s = l16 + 15 - (quad * 4 + r);
        selr[r] = s >> 4;
        srcIdx[r] = (lane & 48) | (s & 15);
    }
    const int T = qb + 17, Ta = T >> 1;
    const int t0 = chunk ? Ta : 0, t1 = chunk ? T : Ta;
    const __hip_bfloat16* rB = rpb + h * 64;

    for (int jt = t0; jt < t1; ++jt) {
        const int j0 = jt * 64;
        // ---- stage K tile (cooperative, 128B-contiguous rows)
#pragma unroll
        for (int pp = 0; pp < 4; ++pp) {
            int cc = pp * 128 + tid, row = cc >> 3, off = (cc & 7) * 8;
            st8(&sk[row][off], ld8(&kbuf[((size_t)(b * KL + j0 + row)) * 1024 + h * 64 + off]));
        }
        // ---- V fragments straight from global
        bf16x8 vvf[4][2];
#pragma unroll
        for (int dt = 0; dt < 4; ++dt) {
            size_t vr = ((size_t)((b * HH + h) * 64 + dt * 16 + l16)) * 2048 + j0 + quad * 8;
            vvf[dt][0] = ld8(&vtb[vr]);
            vvf[dt][1] = ld8(&vtb[vr + 32]);
        }
        // ---- rp band fragments straight from global (clamped rows)
        bf16x8 bF0[6], bF1[6];
        const int ubase = j0 - i0w + 992;
#pragma unroll
        for (int t = 0; t < 6; ++t) {
            int u = ubase + t * 16 + l16;
            if (u > 2047) u = 2047;      // out-of-range -> masked entries only
            const __hip_bfloat16* rr = rB + (size_t)u * 1024 + quad * 8;
            bF0[t] = ld8(rr);
            bF1[t] = ld8(rr + 32);
        }
        __syncthreads();
        // ---- AC = (q + r_w_bias) . k
        f32x4 sfr[2][4];
#pragma unroll
        for (int nt = 0; nt < 4; ++nt) {
            bf16x8 b0 = ld8(&sk[nt * 16 + l16][quad * 8]);
            bf16x8 b1 = ld8(&sk[nt * 16 + l16][32 + quad * 8]);
#pragma unroll
            for (int g = 0; g < 2; ++g) {
                f32x4 z = {};
                z = mfma16(qaw[g][0], b0, z);
                z = mfma16(qaw[g][1], b1, z);
                sfr[g][nt] = z;
            }
        }
        // ---- BD band MFMAs; wave-group g uses frag window t+1-g
#pragma unroll
        for (int g = 0; g < 2; ++g) {
            f32x4 bd[5];
#pragma unroll
            for (int t = 0; t < 5; ++t) {
                int ts = t + 1 - g;
                f32x4 z = {};
                z = mfma16(qar[g][0], bF0[ts], z);
                z = mfma16(qar[g][1], bF1[ts], z);
                bd[t] = z;
            }
            float pre[5][4];
#pragma unroll
            for (int t = 0; t < 5; ++t)
#pragma unroll
                for (int r = 0; r < 4; ++r)
                    pre[t][r] = __shfl(bd[t][r], srcIdx[r], 64);
#pragma unroll
            for (int nt = 0; nt < 4; ++nt)
#pragma unroll
                for (int r = 0; r < 4; ++r) {
                    float bdv = selr[r] ? pre[nt + 1][r] : pre[nt][r];
                    float sv = (sfr[g][nt][r] + bdv) * 0.03125f;
                    int ii = i0w + g * 16 + quad * 4 + r;
                    int jj = j0 + nt * 16 + l16;
                    float p_ = (jj <= ii + ML) ? __expf(sv) : 0.f;
                    spb[wv][g * 16 + quad * 4 + r][nt * 16 + l16] = __float2bfloat16(p_);
                }
        }
        // ---- P @ [V | 1]
#pragma unroll
        for (int g = 0; g < 2; ++g) {
            bf16x8 pa0 = ld8(&spb[wv][g * 16 + l16][quad * 8]);
            bf16x8 pa1 = ld8(&spb[wv][g * 16 + l16][32 + quad * 8]);
            lacc[g] = mfma16(pa0, onesf, lacc[g]);
            lacc[g] = mfma16(pa1, onesf, lacc[g]);
#pragma unroll
            for (int dt = 0; dt < 4; ++dt) {
                oacc[g][dt] = mfma16(pa0, vvf[dt][0], oacc[g][dt]);
                oacc[g][dt] = mfma16(pa1, vvf[dt][1], oacc[g][dt]);
            }
        }
        __syncthreads();
    }
    // ---- unnormalized partial out + l  (group index: chunk*2 + b, 4 groups)
    const size_t obase = ((size_t)((chunk * 2 + b) * HH + h)) * (1024 * 64);
#pragma unroll
    for (int g = 0; g < 2; ++g)
#pragma unroll
        for (int dt = 0; dt < 4; ++dt)
#pragma unroll
            for (int r = 0; r < 4; ++r) {
                int q = i0w + g * 16 + quad * 4 + r;
                Opart[obase + (size_t)q * 64 + dt * 16 + l16] = oacc[g][dt][r];
            }
    if (l16 == 0) {
        const size_t lbase = ((size_t)((chunk * 2 + b) * HH + h)) * 1024;
#pragma unroll
        for (int g = 0; g < 2; ++g)
#pragma unroll
            for (int r = 0; r < 4; ++r) {
                int q = i0w + g * 16 + quad * 4 + r;
                lpart[lbase + q] = lacc[g][r];
            }
    }
}

// combine 2 j-chunks: og = (O0+O1)/(l0+l1), layout [b][q][h*64+d] bf16
__global__ __launch_bounds__(256) void combine_attn(const float* __restrict__ Opart,
                                                    const float* __restrict__ lpart,
                                                    __hip_bfloat16* __restrict__ og) {
    size_t t = (size_t)blockIdx.x * 256 + threadIdx.x;
    size_t e4 = t * 4;
    int d  = (int)(e4 & 63);
    int q  = (int)((e4 >> 6) & 1023);
    int hh = (int)((e4 >> 16) & 15);
    int bb = (int)(e4 >> 20);
    float ox = 0.f, oy = 0.f, oz = 0.f, ow = 0.f, l = 0.f;
#pragma unroll
    for (int c = 0; c < 2; ++c) {
        size_t gsel = (size_t)((c * 2 + bb) * HH + hh);
        float4 o = *(const float4*)&Opart[gsel * (1024 * 64) + (size_t)q * 64 + d];
        ox += o.x; oy += o.y; oz += o.z; ow += o.w;
        l += lpart[gsel * 1024 + q];
    }
    float inv = 1.f / l;
    union { __hip_bfloat16 h[4]; uint2 u; } o;
    o.h[0] = __float2bfloat16(ox * inv);
    o.h[1] = __float2bfloat16(oy * inv);
    o.h[2] = __float2bfloat16(oz * inv);
    o.h[3] = __float2bfloat16(ow * inv);
    *(uint2*)&og[((size_t)bb * 1024 + q) * 1024 + hh * 64 + d] = o.u;
}

// ---------------------------------------------------------------- layernorm
// x = res + sum_{z<NP} parts[z*MN + .] ; out = LN(x); writes f32 + optional bf16
template <int NP, bool WB>
__global__ __launch_bounds__(256) void add_ln_k(const float* __restrict__ res,
                                                const float* __restrict__ parts,
                                                const float* __restrict__ gam,
                                                const float* __restrict__ bet,
                                                float* __restrict__ of,
                                                __hip_bfloat16* __restrict__ ob) {
    const int tid = threadIdx.x;
    const size_t base = (size_t)blockIdx.x * ED;
    const int col = tid * 4;
    float4 va = *(const float4*)&res[base + col];
    float x0 = va.x, x1 = va.y, x2 = va.z, x3 = va.w;
#pragma unroll
    for (int z = 0; z < NP; ++z) {
        float4 p = *(const float4*)&parts[(size_t)z * MN + base + col];
        x0 += p.x; x1 += p.y; x2 += p.z; x3 += p.w;
    }
    float s1 = x0 + x1 + x2 + x3;
    float s2 = x0 * x0 + x1 * x1 + x2 * x2 + x3 * x3;
    for (int o = 32; o > 0; o >>= 1) {
        s1 += __shfl_down(s1, o, 64);
        s2 += __shfl_down(s2, o, 64);
    }
    __shared__ float p1[4], p2[4];
    if ((tid & 63) == 0) { p1[tid >> 6] = s1; p2[tid >> 6] = s2; }
    __syncthreads();
    float S1 = p1[0] + p1[1] + p1[2] + p1[3];
    float S2 = p2[0] + p2[1] + p2[2] + p2[3];
    float mu = S1 * (1.0f / ED);
    float var = S2 * (1.0f / ED) - mu * mu;
    float rs = rsqrtf(var + 1e-3f);
    float4 g4 = *(const float4*)&gam[col];
    float4 b4 = *(const float4*)&bet[col];
    float y0 = (x0 - mu) * rs * g4.x + b4.x;
    float y1 = (x1 - mu) * rs * g4.y + b4.y;
    float y2 = (x2 - mu) * rs * g4.z + b4.z;
    float y3 = (x3 - mu) * rs * g4.w + b4.w;
    *(float4*)&of[base + col] = make_float4(y0, y1, y2, y3);
    if (WB) {
        ob[base + col + 0] = __float2bfloat16(y0);
        ob[base + col + 1] = __float2bfloat16(y1);
        ob[base + col + 2] = __float2bfloat16(y2);
        ob[base + col + 3] = __float2bfloat16(y3);
    }
}

// ---------------------------------------------------------------- launch
extern "C" void kernel_launch(void* const* d_in, const int* in_sizes, int n_in,
                              void* d_out, int out_size, void* d_ws, size_t ws_size,
                              hipStream_t stream) {
    const float* w   = (const float*)d_in[0];
    const float* r   = (const float*)d_in[1];
    const float* mem = (const float*)d_in[2];
    const float* Wq  = (const float*)d_in[4];
    const float* Wk  = (const float*)d_in[5];
    const float* Wv  = (const float*)d_in[6];
    const float* Wr  = (const float*)d_in[7];
    const float* Wo  = (const float*)d_in[8];
    const float* rwb = (const float*)d_in[9];
    const float* rrb = (const float*)d_in[10];
    const float* g1  = (const float*)d_in[11];
    const float* b1  = (const float*)d_in[12];
    const float* W1  = (const float*)d_in[13];
    const float* W2  = (const float*)d_in[14];
    const float* g2  = (const float*)d_in[15];
    const float* b2  = (const float*)d_in[16];

    char* ws = (char*)d_ws;
    size_t off = 0;
    auto alloc = [&](size_t bytes) -> void* {
        void* p = ws + off;
        off += (bytes + 255) & ~(size_t)255;
        return p;
    };
    // persistent
    __hip_bfloat16* wqkvT = (__hip_bfloat16*)alloc((size_t)4096 * 1024 * 2); // Wq|Wk|Wv|Wr ^T
    __hip_bfloat16* wot   = (__hip_bfloat16*)alloc((size_t)ED * ED * 2);
    __hip_bfloat16* w1t   = (__hip_bfloat16*)alloc((size_t)FF * ED * 2);
    __hip_bfloat16* w2t   = (__hip_bfloat16*)alloc((size_t)ED * FF * 2);
    __hip_bfloat16* qwb   = (__hip_bfloat16*)alloc((size_t)BB * QL * ED * 2);
    __hip_bfloat16* qrb   = (__hip_bfloat16*)alloc((size_t)BB * QL * ED * 2);
    __hip_bfloat16* vtb   = (__hip_bfloat16*)alloc((size_t)BB * KL * ED * 2);
    __hip_bfloat16* rpb   = (__hip_bfloat16*)alloc((size_t)KL * ED * 2);
    __hip_bfloat16* og    = (__hip_bfloat16*)alloc((size_t)BB * QL * ED * 2);
    // regionA: cat | xf
    char* regA = (char*)alloc((size_t)BB * KL * ED * 2);
    __hip_bfloat16* cat = (__hip_bfloat16*)regA;
    float*          xf  = (float*)regA;
    // regionB: rbf | xb
    char* regB = (char*)alloc((size_t)KL * ED * 2);
    __hip_bfloat16* rbf = (__hip_bfloat16*)regB;
    __hip_bfloat16* xb  = (__hip_bfloat16*)regB;
    // regionC: kbuf+vbuf | y1
    char* regC = (char*)alloc((size_t)BB * QL * FF * 2);
    __hip_bfloat16* kbuf = (__hip_bfloat16*)regC;
    __hip_bfloat16* vbuf = (__hip_bfloat16*)(regC + (size_t)BB * KL * ED * 2);
    __hip_bfloat16* y1   = (__hip_bfloat16*)regC;
    // regionE: (Opart[4 groups]+lpart) | o_part(4xMN f32) | f_part(4xMN f32)
    const size_t opartBytes = (size_t)4 * HH * QL * 64 * 4;   // 16.8 MB (4 groups)
    const size_t lpartBytes = (size_t)4 * HH * QL * 4;        // 0.25 MB
    size_t regEsz = opartBytes + lpartBytes;
    if (regEsz < (size_t)4 * MN * 4) regEsz = (size_t)4 * MN * 4;
    char* regE = (char*)alloc(regEsz);
    float* Opart  = (float*)regE;
    float* lpart  = (float*)(regE + opartBytes);
    float* o_part = (float*)regE;
    float* f_part = (float*)regE;
    if (off > ws_size) return;  // diagnostic: ws too small -> zeros -> fail loud

    // prep: casts + weight transposes (4 launches)
    build_cat_r<<<3072, 256, 0, stream>>>(w, mem, r, cat, rbf);
    tc5<<<dim3(32, 32, 5), 256, 0, stream>>>(Wq, Wk, Wv, Wr, Wo, wqkvT, wot);
    transpose_cast<<<dim3(128, 32), 256, 0, stream>>>(W1, w1t, 1024, 4096);
    transpose_cast<<<dim3(32, 128), 256, 0, stream>>>(W2, w2t, 4096, 1024);

    // fused Q/K/V/R projection (+Q bias epilogue), exact live grid
    gemm_qkvr<<<dim3(768), 256, 0, stream>>>(cat, rbf, wqkvT, qwb, qrb, kbuf, vbuf, rpb,
                                             rwb, rrb);
    transpose_v<<<dim3(64, 2, 32), 256, 0, stream>>>(vbuf, vtb);

    // attention (r2 grid, no swizzle, slim LDS -> 8 blocks/CU) + combine
    flash_attn7<<<dim3(32, 16, 2), 128, 0, stream>>>(qwb, qrb, kbuf, vtb, rpb, Opart, lpart);
    combine_attn<<<2048, 256, 0, stream>>>(Opart, lpart, og);

    // output projection (split-K 4) + LN1
    gemm_bt<0, true><<<dim3(8, 16, 4), 256, 0, stream>>>(og, wot, o_part, 1024, 256, 1024, 1024);
    add_ln_k<4, true><<<2048, 256, 0, stream>>>(w, o_part, g1, b1, xf, xb);

    // FFN + LN2
    gemm_bt<2, false><<<dim3(32, 16, 1), 256, 0, stream>>>(xb, w1t, y1, 4096, 1024, 1024, 1024);
    gemm_bt<0, true><<<dim3(8, 16, 4), 256, 0, stream>>>(y1, w2t, f_part, 1024, 1024, 4096, 4096);
    add_ln_k<4, false><<<2048, 256, 0, stream>>>(xf, f_part, g2, b2, (float*)d_out, nullptr);
}

// Round 8
// 390.844 us; speedup vs baseline: 1.1794x; 1.0080x over previous
//
#include <hip/hip_runtime.h>
#include <hip/hip_bf16.h>
#include <stdint.h>

typedef __bf16 bf16x8 __attribute__((ext_vector_type(8)));
typedef float  f32x4  __attribute__((ext_vector_type(4)));

constexpr int BB   = 2;
constexpr int QL   = 1024;
constexpr int ML   = 1024;
constexpr int KL   = 2048;
constexpr int ED   = 1024;
constexpr int HH   = 16;
constexpr int FF   = 4096;
constexpr size_t MN = 2048u * 1024u;   // rows x cols of the [B*QL, E] activations

__device__ __forceinline__ bf16x8 ld8(const __hip_bfloat16* p) {
    return *reinterpret_cast<const bf16x8*>(p);
}
__device__ __forceinline__ void st8(__hip_bfloat16* p, bf16x8 v) {
    *reinterpret_cast<bf16x8*>(p) = v;
}
__device__ __forceinline__ f32x4 mfma16(bf16x8 a, bf16x8 b, f32x4 c) {
    return __builtin_amdgcn_mfma_f32_16x16x32_bf16(a, b, c, 0, 0, 0);
}
__device__ __forceinline__ void async16(void* lds, const void* g) {
    __builtin_amdgcn_global_load_lds((__attribute__((address_space(1))) void*)g,
                                     (__attribute__((address_space(3))) void*)lds,
                                     16, 0, 0);
}

// ---------------------------------------------------------------- elementwise
// blocks [0,2048): cat = bf16(concat(member, w));  [2048,3072): rbf = bf16(r)
__global__ __launch_bounds__(256) void build_cat_r(const float* __restrict__ w,
                                                   const float* __restrict__ mem,
                                                   const float* __restrict__ r,
                                                   __hip_bfloat16* __restrict__ cat,
                                                   __hip_bfloat16* __restrict__ rbf) {
    const int bx = blockIdx.x;
    const float* src;
    __hip_bfloat16* dst;
    size_t g;
    if (bx < 2048) {
        size_t t = (size_t)bx * 256 + threadIdx.x;
        g = t * 8;
        int b   = (int)(g >> 21);               // KL*E = 2^21
        int rem = (int)(g & ((1u << 21) - 1));
        int j = rem >> 10, e = rem & 1023;
        src = (j < ML) ? &mem[((size_t)b * ML + j) * ED + e]
                       : &w[((size_t)b * QL + (j - ML)) * ED + e];
        dst = &cat[g];
    } else {
        g = ((size_t)(bx - 2048) * 256 + threadIdx.x) * 8;
        src = &r[g];
        dst = &rbf[g];
    }
    float4 f0 = *(const float4*)src;
    float4 f1 = *(const float4*)(src + 4);
    union { bf16x8 v; __hip_bfloat16 h[8]; } u;
    u.h[0] = __float2bfloat16(f0.x); u.h[1] = __float2bfloat16(f0.y);
    u.h[2] = __float2bfloat16(f0.z); u.h[3] = __float2bfloat16(f0.w);
    u.h[4] = __float2bfloat16(f1.x); u.h[5] = __float2bfloat16(f1.y);
    u.h[6] = __float2bfloat16(f1.z); u.h[7] = __float2bfloat16(f1.w);
    st8(dst, u.v);
}

// ---------------------------------------------------------------- transposes
// ALL 7 weight transposes in one flat launch:
// id<5120: five 1024x1024 (Wq,Wk,Wv,Wr -> wqkvT slots; Wo -> wot)
// [5120,9216): W1 [1024][4096] -> w1t [4096][1024]
// [9216,13312): W2 [4096][1024] -> w2t [1024][4096]
__global__ __launch_bounds__(256) void tc7(const float* __restrict__ Wq, const float* __restrict__ Wk,
                                           const float* __restrict__ Wv, const float* __restrict__ Wr,
                                           const float* __restrict__ Wo, const float* __restrict__ W1,
                                           const float* __restrict__ W2,
                                           __hip_bfloat16* __restrict__ wqkvT,
                                           __hip_bfloat16* __restrict__ wot,
                                           __hip_bfloat16* __restrict__ w1t,
                                           __hip_bfloat16* __restrict__ w2t) {
    __shared__ float tile[32][33];
    const int id = blockIdx.x;
    const float* in;
    __hip_bfloat16* out;
    int K, N, k0, n0;
    if (id < 5120) {
        int z = id >> 10, rem = id & 1023;
        in  = (z == 0) ? Wq : (z == 1) ? Wk : (z == 2) ? Wv : (z == 3) ? Wr : Wo;
        out = (z == 4) ? wot : wqkvT + (size_t)z * 1024 * 1024;
        K = 1024; N = 1024;
        n0 = (rem & 31) * 32; k0 = (rem >> 5) * 32;
    } else if (id < 9216) {
        int local = id - 5120;
        in = W1; out = w1t; K = 1024; N = 4096;
        n0 = (local & 127) * 32; k0 = (local >> 7) * 32;
    } else {
        int local = id - 9216;
        in = W2; out = w2t; K = 4096; N = 1024;
        n0 = (local & 31) * 32; k0 = (local >> 5) * 32;
    }
    const int tx = threadIdx.x & 31, ty = threadIdx.x >> 5;
#pragma unroll
    for (int i = 0; i < 4; ++i)
        tile[ty + i * 8][tx] = in[(size_t)(k0 + ty + i * 8) * N + n0 + tx];
    __syncthreads();
#pragma unroll
    for (int i = 0; i < 4; ++i)
        out[(size_t)(n0 + ty + i * 8) * K + k0 + tx] = __float2bfloat16(tile[tx][ty + i * 8]);
}

// ---------------------------------------------------------------- GEMM core
// C[.,N] = A[.,lda] @ Bt[.,ldb]^T over kLen cols starting at z*kLen (if SK).
// EPI: 0 = f32 out, 2 = bf16 relu out
template <int EPI, bool SK>
__global__ __launch_bounds__(256) void gemm_bt(const __hip_bfloat16* __restrict__ A,
                                               const __hip_bfloat16* __restrict__ Bt,
                                               void* __restrict__ Cv,
                                               int N, int kLen, int lda, int ldb) {
    __shared__ __align__(16) __hip_bfloat16 sA[128 * 32];
    __shared__ __align__(16) __hip_bfloat16 sB[128 * 32];
    const int tid = threadIdx.x;
    const int lane = tid & 63;
    const int l16 = lane & 15, quad = lane >> 4;
    const int wv = tid >> 6;
    const int wm = wv >> 1, wn = wv & 1;
    const int bm = blockIdx.y * 128, bn = blockIdx.x * 128;
    const int kOff = SK ? blockIdx.z * kLen : 0;
    const int c0 = tid, c1 = 256 + tid;
    const int r0 = c0 >> 2, o0 = (c0 & 3) * 8;
    const int r1 = c1 >> 2, o1 = (c1 & 3) * 8;
    f32x4 acc[4][4] = {};
    for (int k0 = 0; k0 < kLen; k0 += 32) {
        async16(&sA[c0 * 8], A + (size_t)(bm + r0) * lda + kOff + k0 + o0);
        async16(&sA[c1 * 8], A + (size_t)(bm + r1) * lda + kOff + k0 + o1);
        async16(&sB[c0 * 8], Bt + (size_t)(bn + r0) * ldb + kOff + k0 + o0);
        async16(&sB[c1 * 8], Bt + (size_t)(bn + r1) * ldb + kOff + k0 + o1);
        __syncthreads();
        bf16x8 af[4], bfr[4];
#pragma unroll
        for (int i = 0; i < 4; ++i)
            af[i] = ld8(&sA[(wm * 64 + i * 16 + l16) * 32 + quad * 8]);
#pragma unroll
        for (int j = 0; j < 4; ++j)
            bfr[j] = ld8(&sB[(wn * 64 + j * 16 + l16) * 32 + quad * 8]);
#pragma unroll
        for (int i = 0; i < 4; ++i)
#pragma unroll
            for (int j = 0; j < 4; ++j)
                acc[i][j] = mfma16(af[i], bfr[j], acc[i][j]);
        __syncthreads();
    }
#pragma unroll
    for (int i = 0; i < 4; ++i)
#pragma unroll
        for (int j = 0; j < 4; ++j)
#pragma unroll
            for (int rg = 0; rg < 4; ++rg) {
                size_t row = bm + wm * 64 + i * 16 + quad * 4 + rg;
                size_t col = bn + wn * 64 + j * 16 + l16;
                float v = acc[i][j][rg];
                if (EPI == 0) {
                    float* C = (float*)Cv + (SK ? (size_t)blockIdx.z * MN : 0);
                    C[row * N + col] = v;
                } else {
                    __hip_bfloat16* C = (__hip_bfloat16*)Cv;
                    C[row * N + col] = __float2bfloat16(fmaxf(v, 0.f));
                }
            }
}

// ---------------------------------------------------------------- fused QKV+R GEMM
// Flat grid of exactly 768 live blocks:
// [0,128) Q (w rows only, +biases) | [128,384) K | [384,640) V (writes vtb
// transposed directly) | [640,768) R
__global__ __launch_bounds__(256) void gemm_qkvr(const __hip_bfloat16* __restrict__ cat,
                                                 const __hip_bfloat16* __restrict__ rbf,
                                                 const __hip_bfloat16* __restrict__ Bt,
                                                 __hip_bfloat16* __restrict__ qwb,
                                                 __hip_bfloat16* __restrict__ qrb,
                                                 __hip_bfloat16* __restrict__ kbuf,
                                                 __hip_bfloat16* __restrict__ vtb,
                                                 __hip_bfloat16* __restrict__ rpb,
                                                 const float* __restrict__ rwb,
                                                 const float* __restrict__ rrb) {
    const int id = blockIdx.x;
    int region, bm, bn;
    if (id < 128) {                      // Q: 16 bm (w rows) x 8 bn
        region = 0;
        int i = id, bmI = i >> 3;
        bm = (bmI >> 3) * 2048 + 1024 + (bmI & 7) * 128;
        bn = (i & 7) * 128;
    } else if (id < 384) {               // K: 32 bm x 8 bn
        region = 1;
        int i = id - 128;
        bm = (i >> 3) * 128;
        bn = (8 + (i & 7)) * 128;
    } else if (id < 640) {               // V: 32 bm x 8 bn
        region = 2;
        int i = id - 384;
        bm = (i >> 3) * 128;
        bn = (16 + (i & 7)) * 128;
    } else {                             // R: 16 bm x 8 bn
        region = 3;
        int i = id - 640;
        bm = (i >> 3) * 128;
        bn = (24 + (i & 7)) * 128;
    }
    const __hip_bfloat16* A = (region == 3) ? rbf : cat;
    __shared__ __align__(16) __hip_bfloat16 sA[128 * 32];
    __shared__ __align__(16) __hip_bfloat16 sB[128 * 32];
    const int tid = threadIdx.x;
    const int lane = tid & 63;
    const int l16 = lane & 15, quad = lane >> 4;
    const int wv = tid >> 6;
    const int wm = wv >> 1, wn = wv & 1;
    const int c0 = tid, c1 = 256 + tid;
    const int r0 = c0 >> 2, o0 = (c0 & 3) * 8;
    const int r1 = c1 >> 2, o1 = (c1 & 3) * 8;
    f32x4 acc[4][4] = {};
    for (int k0 = 0; k0 < 1024; k0 += 32) {
        async16(&sA[c0 * 8], A + (size_t)(bm + r0) * 1024 + k0 + o0);
        async16(&sA[c1 * 8], A + (size_t)(bm + r1) * 1024 + k0 + o1);
        async16(&sB[c0 * 8], Bt + (size_t)(bn + r0) * 1024 + k0 + o0);
        async16(&sB[c1 * 8], Bt + (size_t)(bn + r1) * 1024 + k0 + o1);
        __syncthreads();
        bf16x8 af[4], bfr[4];
#pragma unroll
        for (int i = 0; i < 4; ++i)
            af[i] = ld8(&sA[(wm * 64 + i * 16 + l16) * 32 + quad * 8]);
#pragma unroll
        for (int j = 0; j < 4; ++j)
            bfr[j] = ld8(&sB[(wn * 64 + j * 16 + l16) * 32 + quad * 8]);
#pragma unroll
        for (int i = 0; i < 4; ++i)
#pragma unroll
            for (int j = 0; j < 4; ++j)
                acc[i][j] = mfma16(af[i], bfr[j], acc[i][j]);
        __syncthreads();
    }
#pragma unroll
    for (int j = 0; j < 4; ++j) {
        const int col = bn + wn * 64 + j * 16 + l16;
        float bw = 0.f, br = 0.f;
        if (region == 0) { bw = rwb[col]; br = rrb[col]; }
#pragma unroll
        for (int i = 0; i < 4; ++i)
#pragma unroll
            for (int rg = 0; rg < 4; ++rg) {
                const int row = bm + wm * 64 + i * 16 + quad * 4 + rg;
                const int bb = row >> 11, jr = row & 2047;
                float v = acc[i][j][rg];
                if (region == 0) {
                    size_t o = ((size_t)(bb * 1024 + (jr - 1024))) * 1024 + col;
                    qwb[o] = __float2bfloat16(v + bw);
                    qrb[o] = __float2bfloat16(v + br);
                } else if (region == 1) {
                    kbuf[((size_t)(bb * 2048 + jr)) * 1024 + (col - 1024)] = __float2bfloat16(v);
                } else if (region == 2) {
                    const int cc = col - 2048, hh = cc >> 6, dd = cc & 63;
                    vtb[(((size_t)(bb * HH + hh)) * 64 + dd) * 2048 + jr] = __float2bfloat16(v);
                } else {
                    rpb[(size_t)row * 1024 + (col - 3072)] = __float2bfloat16(v);
                }
            }
    }
}

// ---------------------------------------------------------------- flash attention v8
// = r7 structure (2 waves, LDS-staged K, V+rp frags from global w/ clamp) but
// j-split x4: grid (64,16,2) -> 2048 blocks = 16 waves/CU ceiling (the LDS slim
// in r7 made room; r7's grid of 1024 blocks was the occupancy cap).
__global__ __launch_bounds__(128, 2) void flash_attn8(
        const __hip_bfloat16* __restrict__ qw, const __hip_bfloat16* __restrict__ qr,
        const __hip_bfloat16* __restrict__ kbuf, const __hip_bfloat16* __restrict__ vtb,
        const __hip_bfloat16* __restrict__ rpb,
        float* __restrict__ Opart, float* __restrict__ lpart) {
    __shared__ __align__(16) __hip_bfloat16 sk[64][72];
    __shared__ __align__(16) __hip_bfloat16 spb[2][32][72];
    const int tid = threadIdx.x, wv = tid >> 6, lane = tid & 63;
    const int l16 = lane & 15, quad = lane >> 4;
    const int qb = blockIdx.x >> 2, chunk = blockIdx.x & 3;
    const int h = blockIdx.y, b = blockIdx.z;
    const int i0b = qb * 64, i0w = i0b + wv * 32;

    bf16x8 qaw[2][2], qar[2][2];
#pragma unroll
    for (int g = 0; g < 2; ++g)
#pragma unroll
        for (int kf = 0; kf < 2; ++kf) {
            size_t qi = ((size_t)(b * QL + i0w + g * 16 + l16)) * 1024 + h * 64 + kf * 32 + quad * 8;
            qaw[g][kf] = ld8(&qw[qi]);
            qar[g][kf] = ld8(&qr[qi]);
        }
    f32x4 oacc[2][4] = {};
    f32x4 lacc[2] = {};
    union { bf16x8 v; __hip_bfloat16 h8[8]; } ou;
#pragma unroll
    for (int j = 0; j < 8; ++j) ou.h8[j] = __float2bfloat16(l16 == 0 ? 1.f : 0.f);
    const bf16x8 onesf = ou.v;

    int srcIdx[4], selr[4];
#pragma unroll
    for (int r = 0; r < 4; ++r) {
        int s = l16 + 15 - (quad * 4 + r);
        selr[r] = s >> 4;
        srcIdx[r] = (lane & 48) | (s & 15);
    }
    const int T = qb + 17;
    const int t0 = (chunk * T) >> 2, t1 = ((chunk + 1) * T) >> 2;
    const __hip_bfloat16* rB = rpb + h * 64;

    for (int jt = t0; jt < t1; ++jt) {
        const int j0 = jt * 64;
        // ---- stage K tile (cooperative, 128B-contiguous rows)
#pragma unroll
        for (int pp = 0; pp < 4; ++pp) {
            int cc = pp * 128 + tid, row = cc >> 3, off = (cc & 7) * 8;
            st8(&sk[row][off], ld8(&kbuf[((size_t)(b * KL + j0 + row)) * 1024 + h * 64 + off]));
        }
        // ---- V fragments straight from global
        bf16x8 vvf[4][2];
#pragma unroll
        for (int dt = 0; dt < 4; ++dt) {
            size_t vr = ((size_t)((b * HH + h) * 64 + dt * 16 + l16)) * 2048 + j0 + quad * 8;
            vvf[dt][0] = ld8(&vtb[vr]);
            vvf[dt][1] = ld8(&vtb[vr + 32]);
        }
        // ---- rp band fragments straight from global (clamped rows)
        bf16x8 bF0[6], bF1[6];
        const int ubase = j0 - i0w + 992;
#pragma unroll
        for (int t = 0; t < 6; ++t) {
            int u = ubase + t * 16 + l16;
            if (u > 2047) u = 2047;      // out-of-range -> masked entries only
            const __hip_bfloat16* rr = rB + (size_t)u * 1024 + quad * 8;
            bF0[t] = ld8(rr);
            bF1[t] = ld8(rr + 32);
        }
        __syncthreads();
        // ---- AC = (q + r_w_bias) . k
        f32x4 sfr[2][4];
#pragma unroll
        for (int nt = 0; nt < 4; ++nt) {
            bf16x8 b0 = ld8(&sk[nt * 16 + l16][quad * 8]);
            bf16x8 b1 = ld8(&sk[nt * 16 + l16][32 + quad * 8]);
#pragma unroll
            for (int g = 0; g < 2; ++g) {
                f32x4 z = {};
                z = mfma16(qaw[g][0], b0, z);
                z = mfma16(qaw[g][1], b1, z);
                sfr[g][nt] = z;
            }
        }
        // ---- BD band MFMAs; wave-group g uses frag window t+1-g
#pragma unroll
        for (int g = 0; g < 2; ++g) {
            f32x4 bd[5];
#pragma unroll
            for (int t = 0; t < 5; ++t) {
                int ts = t + 1 - g;
                f32x4 z = {};
                z = mfma16(qar[g][0], bF0[ts], z);
                z = mfma16(qar[g][1], bF1[ts], z);
                bd[t] = z;
            }
            float pre[5][4];
#pragma unroll
            for (int t = 0; t < 5; ++t)
#pragma unroll
                for (int r = 0; r < 4; ++r)
                    pre[t][r] = __shfl(bd[t][r], srcIdx[r], 64);
#pragma unroll
            for (int nt = 0; nt < 4; ++nt)
#pragma unroll
                for (int r = 0; r < 4; ++r) {
                    float bdv = selr[r] ? pre[nt + 1][r] : pre[nt][r];
                    float sv = (sfr[g][nt][r] + bdv) * 0.03125f;
                    int ii = i0w + g * 16 + quad * 4 + r;
                    int jj = j0 + nt * 16 + l16;
                    float p_ = (jj <= ii + ML) ? __expf(sv) : 0.f;
                    spb[wv][g * 16 + quad * 4 + r][nt * 16 + l16] = __float2bfloat16(p_);
                }
        }
        // ---- P @ [V | 1]
#pragma unroll
        for (int g = 0; g < 2; ++g) {
            bf16x8 pa0 = ld8(&spb[wv][g * 16 + l16][quad * 8]);
            bf16x8 pa1 = ld8(&spb[wv][g * 16 + l16][32 + quad * 8]);
            lacc[g] = mfma16(pa0, onesf, lacc[g]);
            lacc[g] = mfma16(pa1, onesf, lacc[g]);
#pragma unroll
            for (int dt = 0; dt < 4; ++dt) {
                oacc[g][dt] = mfma16(pa0, vvf[dt][0], oacc[g][dt]);
                oacc[g][dt] = mfma16(pa1, vvf[dt][1], oacc[g][dt]);
            }
        }
        __syncthreads();
    }
    // ---- unnormalized partial out + l  (group index: chunk*2 + b, 8 groups)
    const size_t obase = ((size_t)((chunk * 2 + b) * HH + h)) * (1024 * 64);
#pragma unroll
    for (int g = 0; g < 2; ++g)
#pragma unroll
        for (int dt = 0; dt < 4; ++dt)
#pragma unroll
            for (int r = 0; r < 4; ++r) {
                int q = i0w + g * 16 + quad * 4 + r;
                Opart[obase + (size_t)q * 64 + dt * 16 + l16] = oacc[g][dt][r];
            }
    if (l16 == 0) {
        const size_t lbase = ((size_t)((chunk * 2 + b) * HH + h)) * 1024;
#pragma unroll
        for (int g = 0; g < 2; ++g)
#pragma unroll
            for (int r = 0; r < 4; ++r) {
                int q = i0w + g * 16 + quad * 4 + r;
                lpart[lbase + q] = lacc[g][r];
            }
    }
}

// combine 4 j-chunks: og = sum(Oc)/sum(lc), layout [b][q][h*64+d] bf16
__global__ __launch_bounds__(256) void combine_attn(const float* __restrict__ Opart,
                                                    const float* __restrict__ lpart,
                                                    __hip_bfloat16* __restrict__ og) {
    size_t t = (size_t)blockIdx.x * 256 + threadIdx.x;
    size_t e4 = t * 4;
    int d  = (int)(e4 & 63);
    int q  = (int)((e4 >> 6) & 1023);
    int hh = (int)((e4 >> 16) & 15);
    int bb = (int)(e4 >> 20);
    float ox = 0.f, oy = 0.f, oz = 0.f, ow = 0.f, l = 0.f;
#pragma unroll
    for (int c = 0; c < 4; ++c) {
        size_t gsel = (size_t)((c * 2 + bb) * HH + hh);
        float4 o = *(const float4*)&Opart[gsel * (1024 * 64) + (size_t)q * 64 + d];
        ox += o.x; oy += o.y; oz += o.z; ow += o.w;
        l += lpart[gsel * 1024 + q];
    }
    float inv = 1.f / l;
    union { __hip_bfloat16 h[4]; uint2 u; } o;
    o.h[0] = __float2bfloat16(ox * inv);
    o.h[1] = __float2bfloat16(oy * inv);
    o.h[2] = __float2bfloat16(oz * inv);
    o.h[3] = __float2bfloat16(ow * inv);
    *(uint2*)&og[((size_t)bb * 1024 + q) * 1024 + hh * 64 + d] = o.u;
}

// ---------------------------------------------------------------- layernorm
// x = res + sum_{z<NP} parts[z*MN + .] ; out = LN(x); writes f32 + optional bf16
template <int NP, bool WB>
__global__ __launch_bounds__(256) void add_ln_k(const float* __restrict__ res,
                                                const float* __restrict__ parts,
                                                const float* __restrict__ gam,
                                                const float* __restrict__ bet,
                                                float* __restrict__ of,
                                                __hip_bfloat16* __restrict__ ob) {
    const int tid = threadIdx.x;
    const size_t base = (size_t)blockIdx.x * ED;
    const int col = tid * 4;
    float4 va = *(const float4*)&res[base + col];
    float x0 = va.x, x1 = va.y, x2 = va.z, x3 = va.w;
#pragma unroll
    for (int z = 0; z < NP; ++z) {
        float4 p = *(const float4*)&parts[(size_t)z * MN + base + col];
        x0 += p.x; x1 += p.y; x2 += p.z; x3 += p.w;
    }
    float s1 = x0 + x1 + x2 + x3;
    float s2 = x0 * x0 + x1 * x1 + x2 * x2 + x3 * x3;
    for (int o = 32; o > 0; o >>= 1) {
        s1 += __shfl_down(s1, o, 64);
        s2 += __shfl_down(s2, o, 64);
    }
    __shared__ float p1[4], p2[4];
    if ((tid & 63) == 0) { p1[tid >> 6] = s1; p2[tid >> 6] = s2; }
    __syncthreads();
    float S1 = p1[0] + p1[1] + p1[2] + p1[3];
    float S2 = p2[0] + p2[1] + p2[2] + p2[3];
    float mu = S1 * (1.0f / ED);
    float var = S2 * (1.0f / ED) - mu * mu;
    float rs = rsqrtf(var + 1e-3f);
    float4 g4 = *(const float4*)&gam[col];
    float4 b4 = *(const float4*)&bet[col];
    float y0 = (x0 - mu) * rs * g4.x + b4.x;
    float y1 = (x1 - mu) * rs * g4.y + b4.y;
    float y2 = (x2 - mu) * rs * g4.z + b4.z;
    float y3 = (x3 - mu) * rs * g4.w + b4.w;
    *(float4*)&of[base + col] = make_float4(y0, y1, y2, y3);
    if (WB) {
        ob[base + col + 0] = __float2bfloat16(y0);
        ob[base + col + 1] = __float2bfloat16(y1);
        ob[base + col + 2] = __float2bfloat16(y2);
        ob[base + col + 3] = __float2bfloat16(y3);
    }
}

// ---------------------------------------------------------------- launch
extern "C" void kernel_launch(void* const* d_in, const int* in_sizes, int n_in,
                              void* d_out, int out_size, void* d_ws, size_t ws_size,
                              hipStream_t stream) {
    const float* w   = (const float*)d_in[0];
    const float* r   = (const float*)d_in[1];
    const float* mem = (const float*)d_in[2];
    const float* Wq  = (const float*)d_in[4];
    const float* Wk  = (const float*)d_in[5];
    const float* Wv  = (const float*)d_in[6];
    const float* Wr  = (const float*)d_in[7];
    const float* Wo  = (const float*)d_in[8];
    const float* rwb = (const float*)d_in[9];
    const float* rrb = (const float*)d_in[10];
    const float* g1  = (const float*)d_in[11];
    const float* b1  = (const float*)d_in[12];
    const float* W1  = (const float*)d_in[13];
    const float* W2  = (const float*)d_in[14];
    const float* g2  = (const float*)d_in[15];
    const float* b2  = (const float*)d_in[16];

    char* ws = (char*)d_ws;
    size_t off = 0;
    auto alloc = [&](size_t bytes) -> void* {
        void* p = ws + off;
        off += (bytes + 255) & ~(size_t)255;
        return p;
    };
    // persistent
    __hip_bfloat16* wqkvT = (__hip_bfloat16*)alloc((size_t)4096 * 1024 * 2); // Wq|Wk|Wv|Wr ^T
    __hip_bfloat16* wot   = (__hip_bfloat16*)alloc((size_t)ED * ED * 2);
    __hip_bfloat16* w1t   = (__hip_bfloat16*)alloc((size_t)FF * ED * 2);
    __hip_bfloat16* w2t   = (__hip_bfloat16*)alloc((size_t)ED * FF * 2);
    __hip_bfloat16* qwb   = (__hip_bfloat16*)alloc((size_t)BB * QL * ED * 2);
    __hip_bfloat16* qrb   = (__hip_bfloat16*)alloc((size_t)BB * QL * ED * 2);
    __hip_bfloat16* vtb   = (__hip_bfloat16*)alloc((size_t)BB * KL * ED * 2);
    __hip_bfloat16* rpb   = (__hip_bfloat16*)alloc((size_t)KL * ED * 2);
    __hip_bfloat16* og    = (__hip_bfloat16*)alloc((size_t)BB * QL * ED * 2);
    // regionA: cat | xf
    char* regA = (char*)alloc((size_t)BB * KL * ED * 2);
    __hip_bfloat16* cat = (__hip_bfloat16*)regA;
    float*          xf  = (float*)regA;
    // regionB: rbf | xb
    char* regB = (char*)alloc((size_t)KL * ED * 2);
    __hip_bfloat16* rbf = (__hip_bfloat16*)regB;
    __hip_bfloat16* xb  = (__hip_bfloat16*)regB;
    // regionC: kbuf | y1
    char* regC = (char*)alloc((size_t)BB * QL * FF * 2);
    __hip_bfloat16* kbuf = (__hip_bfloat16*)regC;
    __hip_bfloat16* y1   = (__hip_bfloat16*)regC;
    // regionE: (Opart[8 groups]+lpart) | o_part(4xMN f32) | f_part(4xMN f32)
    const size_t opartBytes = (size_t)8 * HH * QL * 64 * 4;   // 33.5 MB (8 groups)
    const size_t lpartBytes = (size_t)8 * HH * QL * 4;        // 0.5 MB
    size_t regEsz = opartBytes + lpartBytes;
    if (regEsz < (size_t)4 * MN * 4) regEsz = (size_t)4 * MN * 4;
    char* regE = (char*)alloc(regEsz);
    float* Opart  = (float*)regE;
    float* lpart  = (float*)(regE + opartBytes);
    float* o_part = (float*)regE;
    float* f_part = (float*)regE;
    if (off > ws_size) return;  // diagnostic: ws too small -> zeros -> fail loud

    // prep: casts + all weight transposes (2 launches)
    build_cat_r<<<3072, 256, 0, stream>>>(w, mem, r, cat, rbf);
    tc7<<<13312, 256, 0, stream>>>(Wq, Wk, Wv, Wr, Wo, W1, W2, wqkvT, wot, w1t, w2t);

    // fused Q/K/V/R projection (+Q bias epilogue, V written pre-transposed)
    gemm_qkvr<<<dim3(768), 256, 0, stream>>>(cat, rbf, wqkvT, qwb, qrb, kbuf, vtb, rpb,
                                             rwb, rrb);

    // attention (r7 structure, j-split x4 -> 2048 blocks) + combine
    flash_attn8<<<dim3(64, 16, 2), 128, 0, stream>>>(qwb, qrb, kbuf, vtb, rpb, Opart, lpart);
    combine_attn<<<2048, 256, 0, stream>>>(Opart, lpart, og);

    // output projection (split-K 4) + LN1
    gemm_bt<0, true><<<dim3(8, 16, 4), 256, 0, stream>>>(og, wot, o_part, 1024, 256, 1024, 1024);
    add_ln_k<4, true><<<2048, 256, 0, stream>>>(w, o_part, g1, b1, xf, xb);

    // FFN + LN2
    gemm_bt<2, false><<<dim3(32, 16, 1), 256, 0, stream>>>(xb, w1t, y1, 4096, 1024, 1024, 1024);
    gemm_bt<0, true><<<dim3(8, 16, 4), 256, 0, stream>>>(y1, w2t, f_part, 1024, 1024, 4096, 4096);
    add_ln_k<4, false><<<2048, 256, 0, stream>>>(xf, f_part, g2, b2, (float*)d_out, nullptr);
}